// Round 1
// baseline (2227.683 us; speedup 1.0000x reference)
//
#include <hip/hip_runtime.h>

typedef __bf16 bf16;
typedef __attribute__((ext_vector_type(8))) __bf16 bf16x8;
typedef __attribute__((ext_vector_type(4))) float f32x4;

#define SEQ 4096
#define DM  1024
#define NH  16
#define DH  64

// ---------------------------------------------------------------------------
// Generic bt-GEMM: C[m][n] = scale * sum_k A[m][k]*B[n][k] + bias[n]
// A: fp32 or bf16 (converted during LDS staging), B: bf16 (pre-transposed),
// C: fp32 or bf16. MFMA 16x16x32 bf16, fp32 accumulate.
// Verified layouts (learn_hip m89/m91/m92): A/B frag: lane holds
// [m|n = lane&15][k = (lane>>4)*8 + j] (8 contiguous bf16);
// C/D: col = lane&15, row = (lane>>4)*4 + reg.
// ---------------------------------------------------------------------------
template<int BM, int BN, int BK, int WM, int WN, int TM, int TN,
         typename AT, typename CT>
__global__ __launch_bounds__(WM*WN*64) void gemm_bt(
    const AT* __restrict__ A, long lda, long sAb,
    const bf16* __restrict__ B, long ldb, long sBb,
    CT* __restrict__ C, long ldc, long sCb,
    const float* __restrict__ bias, float scale, int K)
{
  static_assert(BM == WM*16*TM && BN == WN*16*TN, "tile mismatch");
  constexpr int NT = WM*WN*64;
  constexpr int LDP = BK + 8;              // +8 bf16 pad: row stride 144 B (16B-aligned, 2-way-max bank alias)
  __shared__ bf16 As[BM][LDP];
  __shared__ bf16 Bs[BN][LDP];

  const int tid  = threadIdx.x;
  const int lane = tid & 63;
  const int wave = tid >> 6;
  const int wm   = wave % WM;
  const int wn   = wave / WM;
  const int tr   = lane & 15;
  const int quad = lane >> 4;

  A += (long)blockIdx.z * sAb + (long)blockIdx.x * BM * lda;
  B += (long)blockIdx.z * sBb + (long)blockIdx.y * BN * ldb;
  C += (long)blockIdx.z * sCb;

  f32x4 acc[TM][TN] = {};

  for (int k0 = 0; k0 < K; k0 += BK) {
    // ---- stage A tile ----
    if constexpr (sizeof(AT) == 4) {
      #pragma unroll
      for (int i = tid; i < BM*(BK/4); i += NT) {
        int r = i / (BK/4), c = (i % (BK/4)) * 4;
        const float4 f = *(const float4*)(A + (long)r*lda + k0 + c);
        As[r][c+0] = (bf16)f.x; As[r][c+1] = (bf16)f.y;
        As[r][c+2] = (bf16)f.z; As[r][c+3] = (bf16)f.w;
      }
    } else {
      #pragma unroll
      for (int i = tid; i < BM*(BK/8); i += NT) {
        int r = i / (BK/8), c = (i % (BK/8)) * 8;
        *(bf16x8*)&As[r][c] = *(const bf16x8*)(A + (long)r*lda + k0 + c);
      }
    }
    // ---- stage B tile ----
    #pragma unroll
    for (int i = tid; i < BN*(BK/8); i += NT) {
      int r = i / (BK/8), c = (i % (BK/8)) * 8;
      *(bf16x8*)&Bs[r][c] = *(const bf16x8*)(B + (long)r*ldb + k0 + c);
    }
    __syncthreads();

    #pragma unroll
    for (int kk = 0; kk < BK; kk += 32) {
      bf16x8 af[TM], bfr[TN];
      #pragma unroll
      for (int i = 0; i < TM; ++i)
        af[i] = *(const bf16x8*)&As[wm*16*TM + i*16 + tr][kk + quad*8];
      #pragma unroll
      for (int j = 0; j < TN; ++j)
        bfr[j] = *(const bf16x8*)&Bs[wn*16*TN + j*16 + tr][kk + quad*8];
      #pragma unroll
      for (int i = 0; i < TM; ++i)
        #pragma unroll
        for (int j = 0; j < TN; ++j)
          acc[i][j] = __builtin_amdgcn_mfma_f32_16x16x32_bf16(af[i], bfr[j], acc[i][j], 0, 0, 0);
    }
    __syncthreads();
  }

  // ---- epilogue ----
  #pragma unroll
  for (int i = 0; i < TM; ++i) {
    #pragma unroll
    for (int j = 0; j < TN; ++j) {
      const int row0 = blockIdx.x*BM + wm*16*TM + i*16 + quad*4;
      const int col  = blockIdx.y*BN + wn*16*TN + j*16 + tr;
      const float bv = bias ? bias[col] : 0.f;
      #pragma unroll
      for (int r = 0; r < 4; ++r) {
        float v = acc[i][j][r] * scale + bv;
        C[(long)(row0 + r)*ldc + col] = (CT)v;
      }
    }
  }
}

// ---------------------------------------------------------------------------
// Transpose src[R][Cc] -> dst[Cc][R], casting to bf16. block (32,8).
// ---------------------------------------------------------------------------
template<typename T>
__global__ void transpose_to_bf16(const T* __restrict__ src, bf16* __restrict__ dst,
                                  int R, int Cc)
{
  __shared__ T tile[32][33];
  const int c0 = blockIdx.x * 32, r0 = blockIdx.y * 32;
  const int tx = threadIdx.x, ty = threadIdx.y;
  #pragma unroll
  for (int i = ty; i < 32; i += 8)
    tile[i][tx] = src[(long)(r0 + i)*Cc + c0 + tx];
  __syncthreads();
  #pragma unroll
  for (int i = ty; i < 32; i += 8)
    dst[(long)(c0 + i)*R + r0 + tx] = (bf16)tile[tx][i];
}

// ---------------------------------------------------------------------------
// In-place row softmax: p[row][0..4095], one 256-thread block per row.
// ---------------------------------------------------------------------------
__global__ __launch_bounds__(256) void softmax_rows(float* __restrict__ p)
{
  constexpr int NC = 4096;
  __shared__ float buf[NC];
  __shared__ float red[8];
  float* rp = p + (long)blockIdx.x * NC;
  const int tid = threadIdx.x;

  float lmax = -1e30f;
  #pragma unroll
  for (int i = tid; i < NC/4; i += 256) {
    float4 f = ((const float4*)rp)[i];
    ((float4*)buf)[i] = f;
    lmax = fmaxf(lmax, fmaxf(fmaxf(f.x, f.y), fmaxf(f.z, f.w)));
  }
  #pragma unroll
  for (int o = 32; o; o >>= 1) lmax = fmaxf(lmax, __shfl_xor(lmax, o, 64));
  if ((tid & 63) == 0) red[tid >> 6] = lmax;
  __syncthreads();
  const float m = fmaxf(fmaxf(red[0], red[1]), fmaxf(red[2], red[3]));

  float lsum = 0.f;
  #pragma unroll
  for (int i = tid; i < NC/4; i += 256) {
    float4 f = ((float4*)buf)[i];
    f.x = __expf(f.x - m); f.y = __expf(f.y - m);
    f.z = __expf(f.z - m); f.w = __expf(f.w - m);
    ((float4*)buf)[i] = f;
    lsum += (f.x + f.y) + (f.z + f.w);
  }
  #pragma unroll
  for (int o = 32; o; o >>= 1) lsum += __shfl_xor(lsum, o, 64);
  if ((tid & 63) == 0) red[4 + (tid >> 6)] = lsum;
  __syncthreads();
  const float inv = 1.f / (((red[4] + red[5]) + (red[6] + red[7])));

  #pragma unroll
  for (int i = tid; i < NC/4; i += 256) {
    float4 f = ((float4*)buf)[i];
    f.x *= inv; f.y *= inv; f.z *= inv; f.w *= inv;
    ((float4*)rp)[i] = f;
  }
}

// ---------------------------------------------------------------------------
extern "C" void kernel_launch(void* const* d_in, const int* in_sizes, int n_in,
                              void* d_out, int out_size, void* d_ws, size_t ws_size,
                              hipStream_t stream)
{
  const float* q  = (const float*)d_in[0];
  const float* k  = (const float*)d_in[1];
  const float* v  = (const float*)d_in[2];
  const float* Wq = (const float*)d_in[3];
  const float* bq = (const float*)d_in[4];
  const float* Wk = (const float*)d_in[5];
  const float* bk = (const float*)d_in[6];
  const float* Wv = (const float*)d_in[7];
  const float* bv = (const float*)d_in[8];
  const float* Wo = (const float*)d_in[9];
  const float* bo = (const float*)d_in[10];

  float* out  = (float*)d_out;                 // [4096][1024] fp32
  float* attn = out + (long)SEQ * DM;          // [16][4096][4096] fp32

  // workspace layout (48 MB total)
  char* ws = (char*)d_ws;
  bf16* WqT = (bf16*)(ws + 0l*(1l<<21));       // [1024][1024] bf16, Wt[n][k]=W[k][n]
  bf16* WkT = (bf16*)(ws + 1l*(1l<<21));
  bf16* WvT = (bf16*)(ws + 2l*(1l<<21));
  bf16* WoT = (bf16*)(ws + 3l*(1l<<21));
  bf16* Qb  = (bf16*)(ws + 1l*(1l<<23));       // [4096][1024] bf16 projected
  bf16* Kb  = (bf16*)(ws + 2l*(1l<<23));
  bf16* Vb  = (bf16*)(ws + 3l*(1l<<23));
  bf16* Vt  = (bf16*)(ws + 4l*(1l<<23));       // [1024][4096] = V^T
  bf16* Cc  = (bf16*)(ws + 5l*(1l<<23));       // [4096][1024] concat

  const dim3 tb(32, 8);

  // 1) weights -> bf16 transposed (bt layout)
  transpose_to_bf16<float><<<dim3(32, 32), tb, 0, stream>>>(Wq, WqT, DM, DM);
  transpose_to_bf16<float><<<dim3(32, 32), tb, 0, stream>>>(Wk, WkT, DM, DM);
  transpose_to_bf16<float><<<dim3(32, 32), tb, 0, stream>>>(Wv, WvT, DM, DM);
  transpose_to_bf16<float><<<dim3(32, 32), tb, 0, stream>>>(Wo, WoT, DM, DM);

  // 2) projections: Qb = q@Wq+bq (fp32 A converted in staging, bf16 out)
  gemm_bt<128,128,64,2,2,4,4,float,bf16><<<dim3(32, 8, 1), 256, 0, stream>>>(
      q, DM, 0, WqT, DM, 0, Qb, DM, 0, bq, 1.f, DM);
  gemm_bt<128,128,64,2,2,4,4,float,bf16><<<dim3(32, 8, 1), 256, 0, stream>>>(
      k, DM, 0, WkT, DM, 0, Kb, DM, 0, bk, 1.f, DM);
  gemm_bt<128,128,64,2,2,4,4,float,bf16><<<dim3(32, 8, 1), 256, 0, stream>>>(
      v, DM, 0, WvT, DM, 0, Vb, DM, 0, bv, 1.f, DM);

  // 3) V^T for the PV gemm (B operand needs [n][k] = [d][s])
  transpose_to_bf16<bf16><<<dim3(DM/32, SEQ/32), tb, 0, stream>>>(Vb, Vt, SEQ, DM);

  // 4) scores = (Qh Kh^T)/8 -> unnormalized into attn region (batched over heads)
  gemm_bt<128,128,64,2,2,4,4,bf16,float><<<dim3(32, 32, NH), 256, 0, stream>>>(
      Qb, DM, DH, Kb, DM, DH, attn, SEQ, (long)SEQ*SEQ, nullptr, 0.125f, DH);

  // 5) softmax in place over 16*4096 rows
  softmax_rows<<<NH*SEQ, 256, 0, stream>>>(attn);

  // 6) vals = attn @ Vh -> concat[s][h*64+d] bf16
  gemm_bt<128,64,64,2,2,4,2,float,bf16><<<dim3(32, 1, NH), 256, 0, stream>>>(
      attn, SEQ, (long)SEQ*SEQ, Vt, SEQ, (long)DH*SEQ, Cc, DM, DH, nullptr, 1.f, SEQ);

  // 7) out = concat @ Wo + bo
  gemm_bt<128,128,64,2,2,4,4,bf16,float><<<dim3(32, 8, 1), 256, 0, stream>>>(
      Cc, DM, 0, WoT, DM, 0, out, DM, 0, bo, 1.f, DM);
}